// Round 4
// baseline (16.270 us; speedup 1.0000x reference)
//
#include <hip/hip_runtime.h>
#include <math.h>

// QuanConv2D collapsed form:
//   d_k = alpha_k*cos(pi*x_k) + beta_k*sin(pi*x_k)   (per patch element k=0..3)
//   out0 = d1*d2*d3, out1 = d0*d1, out2 = d0*d1*d2, out3 = d0*d1*d2*d3
// Fused single dispatch; coeffs per-block in LDS; native v_sin/v_cos (revolutions).
// Layout: 2 patches/thread -> every global load/store is lane-contiguous.

#define W_MUL 0.632455532033675866f  // sqrt(2/5)

struct cplx { float x, y; };
__device__ inline cplx cmul(cplx a, cplx b) { return {a.x*b.x - a.y*b.y, a.x*b.y + a.y*b.x}; }
__device__ inline cplx cadd(cplx a, cplx b) { return {a.x + b.x, a.y + b.y}; }
__device__ inline float cabs2(cplx a) { return a.x*a.x + a.y*a.y; }

__device__ inline float dval(float x, float A, float B) {
    // sin(pi*x) = v_sin(x/2 rev), cos(pi*x) = v_cos(x/2 rev); x in [0,1)
    const float h = 0.5f * x;
    const float s = __builtin_amdgcn_sinf(h);
    const float c = __builtin_amdgcn_cosf(h);
    return fmaf(A, c, B * s);
}

// B=32, H=W=512, Ho=Wo=256. One thread handles 2 horizontal patches:
// float4 from row 2i (cols 4j..4j+3) + float4 from row 2i+1 -> 2 output cols
// in each of 4 planes. Lane i accesses base+16*i on loads (1KB/wave instr)
// and base+8*i on stores (512B/wave instr) -> zero wasted span.
__global__ __launch_bounds__(256, 8) void quanconv_fused(const float* __restrict__ in,
                                                         const float* __restrict__ w,
                                                         float* __restrict__ out) {
    __shared__ float sc[8];

    const int tid = blockIdx.x * 256 + threadIdx.x;   // 0 .. 32*256*128-1
    const int j2 = tid & 127;          // horizontal patch-pair index
    const int i  = (tid >> 7) & 255;   // output row
    const int b  = tid >> 15;          // batch

    // Issue global loads FIRST so VMEM latency overlaps coeff compute + sync.
    const float* p = in + ((size_t)b << 18) + ((size_t)i << 10) + (j2 << 2);
    const float4 r0 = *(const float4*)p;          // row 2i,   cols 4j2..4j2+3
    const float4 r1 = *(const float4*)(p + 512);  // row 2i+1

    if (threadIdx.x < 4) {
        const int k = threadIdx.x;
        float t0 = w[3*k+0] * W_MUL;
        float t1 = w[3*k+1] * W_MUL;
        float t2 = w[3*k+2] * W_MUL;
        float c0 = cosf(0.5f*t0), s0 = sinf(0.5f*t0);
        float c1 = cosf(0.5f*t1), s1 = sinf(0.5f*t1);
        float c2v = cosf(0.5f*t2), s2 = sinf(0.5f*t2);
        // Rx(t) = [[c, -i s], [-i s, c]];  Rz(t) = [[e^{-it/2}, 0], [0, e^{+it/2}]]
        cplx Rx0[2][2] = {{{c0, 0.f}, {0.f, -s0}}, {{0.f, -s0}, {c0, 0.f}}};
        cplx Rz1[2][2] = {{{c1, -s1}, {0.f, 0.f}}, {{0.f, 0.f}, {c1, s1}}};
        cplx Rx2[2][2] = {{{c2v, 0.f}, {0.f, -s2}}, {{0.f, -s2}, {c2v, 0.f}}};
        cplx M[2][2], G[2][2];
        for (int ii = 0; ii < 2; ++ii)
            for (int jj = 0; jj < 2; ++jj) {
                cplx acc = {0.f, 0.f};
                for (int l = 0; l < 2; ++l) acc = cadd(acc, cmul(Rz1[ii][l], Rx0[l][jj]));
                M[ii][jj] = acc;
            }
        for (int ii = 0; ii < 2; ++ii)
            for (int jj = 0; jj < 2; ++jj) {
                cplx acc = {0.f, 0.f};
                for (int l = 0; l < 2; ++l) acc = cadd(acc, cmul(Rx2[ii][l], M[l][jj]));
                G[ii][jj] = acc;
            }
        // alpha = d at x=0 (a=(1,0));  beta = d at x=1/2 (a=(r,r), r=sqrt(1/2))
        sc[k]     = cabs2(G[0][0]) - cabs2(G[1][0]);
        cplx u0 = cadd(G[0][0], G[0][1]);
        cplx u1 = cadd(G[1][0], G[1][1]);
        sc[4 + k] = 0.5f * (cabs2(u0) - cabs2(u1));
    }
    __syncthreads();

    const float A0 = sc[0], A1 = sc[1], A2 = sc[2], A3 = sc[3];
    const float B0 = sc[4], B1 = sc[5], B2 = sc[6], B3 = sc[7];

    // patch A: x0=r0.x x1=r0.y x2=r1.x x3=r1.y ; patch B: r0.z r0.w r1.z r1.w
    const float dA0 = dval(r0.x, A0, B0);
    const float dA1 = dval(r0.y, A1, B1);
    const float dA2 = dval(r1.x, A2, B2);
    const float dA3 = dval(r1.y, A3, B3);
    const float dB0 = dval(r0.z, A0, B0);
    const float dB1 = dval(r0.w, A1, B1);
    const float dB2 = dval(r1.z, A2, B2);
    const float dB3 = dval(r1.w, A3, B3);

    const float pA01  = dA0 * dA1;
    const float pA012 = pA01 * dA2;
    const float pB01  = dB0 * dB1;
    const float pB012 = pB01 * dB2;

    float* o = out + ((size_t)b << 18) + ((size_t)i << 8) + (j2 << 1);
    *(float2*)(o)             = {dA1 * dA2 * dA3, dB1 * dB2 * dB3};
    *(float2*)(o + (1 << 16)) = {pA01,            pB01};
    *(float2*)(o + (2 << 16)) = {pA012,           pB012};
    *(float2*)(o + (3 << 16)) = {pA012 * dA3,     pB012 * dB3};
}

extern "C" void kernel_launch(void* const* d_in, const int* in_sizes, int n_in,
                              void* d_out, int out_size, void* d_ws, size_t ws_size,
                              hipStream_t stream) {
    const float* input  = (const float*)d_in[0];
    const float* weight = (const float*)d_in[1];
    float* out = (float*)d_out;
    quanconv_fused<<<4096, 256, 0, stream>>>(input, weight, out);
}